// Round 5
// baseline (3843.445 us; speedup 1.0000x reference)
//
#include <hip/hip_runtime.h>

#define N_NODES 10000
#define N_EDGES 320000
#define NODE_DIM 128
#define EDGE_DIM 16
#define HIDDEN 256
#define N_OUT 8
#define N_GRAPHS 64
#define LOG2E 1.4426950408889634f

typedef float f32x4 __attribute__((ext_vector_type(4)));
typedef float f32x16 __attribute__((ext_vector_type(16)));
typedef short bf16x8 __attribute__((ext_vector_type(8)));
typedef unsigned short u16x8 __attribute__((ext_vector_type(8)));

__device__ __forceinline__ unsigned short f2bf(float f) {
  unsigned int u = __float_as_uint(f);
  unsigned int r = (u + 0x7fff + ((u >> 16) & 1)) >> 16;
  return (unsigned short)r;
}

// ---------------- CSR build ----------------
__global__ void hist_kernel(const int* __restrict__ dst, int* __restrict__ counts, int E) {
  int e = blockIdx.x * blockDim.x + threadIdx.x;
  if (e < E) atomicAdd(&counts[dst[e]], 1);
}

__global__ void scan_kernel(const int* __restrict__ counts, int* __restrict__ offs,
                            int* __restrict__ cursor, int n) {
  __shared__ int part[256];
  int t = threadIdx.x;
  const int chunk = (n + 255) / 256;
  int base = t * chunk;
  int s = 0;
  for (int j = 0; j < chunk; ++j) { int i = base + j; if (i < n) s += counts[i]; }
  part[t] = s;
  __syncthreads();
  for (int off = 1; off < 256; off <<= 1) {
    int v = (t >= off) ? part[t - off] : 0;
    __syncthreads();
    part[t] += v;
    __syncthreads();
  }
  int run = (t == 0) ? 0 : part[t - 1];
  for (int j = 0; j < chunk; ++j) {
    int i = base + j;
    if (i < n) { offs[i] = run; cursor[i] = run; run += counts[i]; }
  }
  if (t == 255) offs[n] = run;
}

// scatter edges into CSR order; edge attr converted to bf16 [E][16]
__global__ void scatter_kernel(const int* __restrict__ ei, const float* __restrict__ eattr,
                               int* __restrict__ cursor, int* __restrict__ csr_src,
                               unsigned short* __restrict__ attr_bf, int E) {
  int e = blockIdx.x * blockDim.x + threadIdx.x;
  if (e >= E) return;
  int s = ei[e];
  int d = ei[E + e];
  int slot = atomicAdd(&cursor[d], 1);
  csr_src[slot] = s;
  const float4* in = (const float4*)(eattr + (size_t)e * 16);
  float4 v0 = in[0], v1 = in[1], v2 = in[2], v3 = in[3];
  u16x8 o0, o1;
  o0[0] = f2bf(v0.x); o0[1] = f2bf(v0.y); o0[2] = f2bf(v0.z); o0[3] = f2bf(v0.w);
  o0[4] = f2bf(v1.x); o0[5] = f2bf(v1.y); o0[6] = f2bf(v1.z); o0[7] = f2bf(v1.w);
  o1[0] = f2bf(v2.x); o1[1] = f2bf(v2.y); o1[2] = f2bf(v2.z); o1[3] = f2bf(v2.w);
  o1[4] = f2bf(v3.x); o1[5] = f2bf(v3.y); o1[6] = f2bf(v3.z); o1[7] = f2bf(v3.w);
  u16x8* outp = (u16x8*)(attr_bf + (size_t)slot * 16);
  outp[0] = o0; outp[1] = o1;
}

// ---------------- weight / activation bf16 conversion ----------------
// WT[n][k] = (n<256 ? Wl[k][n] : Wr[k][n-256]) as bf16, n in [0,512)
__global__ void cvt_w(const float* __restrict__ Wl, const float* __restrict__ Wr,
                      unsigned short* __restrict__ WT, int K) {
  int idx = blockIdx.x * 256 + threadIdx.x;
  if (idx >= 512 * K) return;
  int n = idx / K, k = idx - n * K;
  float v = (n < 256) ? Wl[(size_t)k * 256 + n] : Wr[(size_t)k * 256 + (n - 256)];
  WT[idx] = f2bf(v);
}

__global__ void cvt_x(const float* __restrict__ X, unsigned short* __restrict__ XB, int total4) {
  int idx = blockIdx.x * 256 + threadIdx.x;
  if (idx >= total4) return;
  float4 v = *(const float4*)(X + (size_t)idx * 4);
  ushort4 o;
  o.x = f2bf(v.x); o.y = f2bf(v.y); o.z = f2bf(v.z); o.w = f2bf(v.w);
  *(ushort4*)(XB + (size_t)idx * 4) = o;
}

// WeT[layer][col][k] bf16: transposed We for B-fragments of the edge MFMA
__global__ void cvt_we(const float* __restrict__ We1, const float* __restrict__ Wes,
                       unsigned short* __restrict__ WeT) {
  int idx = blockIdx.x * 256 + threadIdx.x;  // layer*256 + col
  if (idx >= 5 * 256) return;
  int layer = idx >> 8, col = idx & 255;
  const float* W = (layer == 0) ? We1 : Wes + (size_t)(layer - 1) * EDGE_DIM * HIDDEN;
  u16x8 a, b;
#pragma unroll
  for (int k = 0; k < 8; ++k) {
    a[k] = f2bf(W[k * 256 + col]);
    b[k] = f2bf(W[(k + 8) * 256 + col]);
  }
  u16x8* o = (u16x8*)(WeT + (size_t)idx * 16);
  o[0] = a; o[1] = b;
}

// ---------------- MFMA node GEMM: C[M][512] = A[M][K](bf16) @ W[K][512](bf16,WT=col-major) ----------------
__global__ __launch_bounds__(256) void gemm_mfma(
    const unsigned short* __restrict__ A,   // [M][K] bf16 row-major
    const unsigned short* __restrict__ WT,  // [512][K] bf16 (output-col major)
    const float* __restrict__ bl, const float* __restrict__ br,
    float* __restrict__ C, int M, int K) {
  const int t = threadIdx.x;
  const int wv = t >> 6;
  const int l = t & 63;
  const int bm = blockIdx.x * 64;
  const int bn = blockIdx.y * 64;
  const int col = bn + wv * 16 + (l & 15);
  const int kgrp = (l >> 4) * 8;
  f32x4 acc[4];
#pragma unroll
  for (int mt = 0; mt < 4; ++mt) acc[mt] = (f32x4){0.f, 0.f, 0.f, 0.f};

  int arow[4];
#pragma unroll
  for (int mt = 0; mt < 4; ++mt) {
    int r = bm + mt * 16 + (l & 15);
    arow[mt] = (r < M) ? r : M - 1;
  }

  for (int k0 = 0; k0 < K; k0 += 32) {
    bf16x8 bfrag = *(const bf16x8*)(WT + (size_t)col * K + k0 + kgrp);
#pragma unroll
    for (int mt = 0; mt < 4; ++mt) {
      bf16x8 afrag = *(const bf16x8*)(A + (size_t)arow[mt] * K + k0 + kgrp);
      acc[mt] = __builtin_amdgcn_mfma_f32_16x16x32_bf16(afrag, bfrag, acc[mt], 0, 0, 0);
    }
  }
  const float bias = (col < 256) ? bl[col] : br[col - 256];
#pragma unroll
  for (int mt = 0; mt < 4; ++mt) {
#pragma unroll
    for (int j = 0; j < 4; ++j) {
      int row = bm + mt * 16 + (l >> 4) * 4 + j;
      if (row < M) C[(size_t)row * 512 + col] = acc[mt][j] + bias;
    }
  }
}

// ---------------- MFMA edge kernel ----------------
// One wave per dst node; 32-edge tiles via mfma_f32_32x32x16_bf16 (K=16=EDGE_DIM):
// E-tile[32 edges][256 cols] = attr_tile @ We, C-init = broadcast xr.
// Lane l: col c = l&31 (+nt*32), rows r(j) = (j&3)+8*(j>>2)+4*(l>>5).
// Score p[row] = sum_col att[col]*leaky(E+xl); 5-round xor-reduce over 32 col-lanes.
// Online softmax per tile; alpha-weighted xl accumulation (L1-hot reload).
__global__ __launch_bounds__(256, 3) void edge_gat(
    const float* __restrict__ xlr,
    const int* __restrict__ offs, const int* __restrict__ csr_src,
    const unsigned short* __restrict__ attr_bf,
    const unsigned short* __restrict__ WeT, const float* __restrict__ att,
    const float* __restrict__ bconv,
    const float* __restrict__ gamma, const float* __restrict__ beta,
    const float* __restrict__ mean, const float* __restrict__ var,
    float* __restrict__ hout, unsigned short* __restrict__ hbf, int relu_last) {
  const int t = threadIdx.x;
  const int wv = t >> 6;
  const int l = t & 63;
  const int c = l & 31;
  const int h = l >> 5;
  const int i = __builtin_amdgcn_readfirstlane(blockIdx.x * 4 + wv);

  bf16x8 Bf[8];
#pragma unroll
  for (int nt = 0; nt < 8; ++nt)
    Bf[nt] = *(const bf16x8*)(WeT + (size_t)(nt * 32 + c) * 16 + h * 8);
  float xr_c[8], att_c[8];
#pragma unroll
  for (int nt = 0; nt < 8; ++nt) {
    xr_c[nt] = xlr[(size_t)i * 512 + 256 + nt * 32 + c];
    att_c[nt] = att[nt * 32 + c] * LOG2E;
  }
  const int rs = __builtin_amdgcn_readfirstlane(offs[i]);
  const int re = __builtin_amdgcn_readfirstlane(offs[i + 1]);

  float out_c[8];
#pragma unroll
  for (int nt = 0; nt < 8; ++nt) out_c[nt] = 0.f;
  float den = 0.f, mrun = -1e30f;

  for (int base = rs; base < re; base += 32) {
    int ea = base + c;
    if (ea >= re) ea = re - 1;
    bf16x8 af = *(const bf16x8*)(attr_bf + (size_t)ea * 16 + h * 8);

    int eoff[16];
#pragma unroll
    for (int j = 0; j < 16; ++j) {
      int r = (j & 3) + 8 * (j >> 2) + 4 * h;
      int er = base + r;
      if (er >= re) er = re - 1;
      eoff[j] = csr_src[er] * 512 + c;
    }

    float p[16];
#pragma unroll
    for (int j = 0; j < 16; ++j) p[j] = 0.f;

#pragma unroll
    for (int nt = 0; nt < 8; ++nt) {
      f32x16 acc;
#pragma unroll
      for (int j = 0; j < 16; ++j) acc[j] = xr_c[nt];
      acc = __builtin_amdgcn_mfma_f32_32x32x16_bf16(af, Bf[nt], acc, 0, 0, 0);
#pragma unroll
      for (int j = 0; j < 16; ++j) {
        float xl = xlr[eoff[j] + nt * 32];
        float z = acc[j] + xl;
        z = fmaxf(z, 0.2f * z);
        p[j] = fmaf(att_c[nt], z, p[j]);
      }
    }

#pragma unroll
    for (int m = 1; m <= 16; m <<= 1) {
#pragma unroll
      for (int j = 0; j < 16; ++j) p[j] += __shfl_xor(p[j], m, 64);
    }
#pragma unroll
    for (int j = 0; j < 16; ++j) {
      int r = (j & 3) + 8 * (j >> 2) + 4 * h;
      if (base + r >= re) p[j] = -1e30f;
    }
    float tm = p[0];
#pragma unroll
    for (int j = 1; j < 16; ++j) tm = fmaxf(tm, p[j]);
    tm = fmaxf(tm, __shfl_xor(tm, 32, 64));
    const float nm = fmaxf(mrun, tm);
    const float sc = exp2f(mrun - nm);
    mrun = nm;
    float w[16], wsum = 0.f;
#pragma unroll
    for (int j = 0; j < 16; ++j) {
      w[j] = exp2f(p[j] - nm);
      wsum += w[j];
    }
    den = fmaf(den, sc, wsum);
#pragma unroll
    for (int nt = 0; nt < 8; ++nt) {
      float tacc = 0.f;
#pragma unroll
      for (int j = 0; j < 16; ++j) tacc = fmaf(w[j], xlr[eoff[j] + nt * 32], tacc);
      out_c[nt] = fmaf(out_c[nt], sc, tacc);
    }
  }

  den += __shfl_xor(den, 32, 64);
  const float inv = (den > 0.f) ? __frcp_rn(den) : 0.f;
#pragma unroll
  for (int nt = 0; nt < 8; ++nt) {
    float o = out_c[nt] + __shfl_xor(out_c[nt], 32, 64);
    const int col = nt * 32 + c;
    o = fmaf(o, inv, bconv[col]);
    o = (o - mean[col]) * rsqrtf(var[col] + 1e-5f) * gamma[col] + beta[col];
    o = relu_last ? fmaxf(o, 0.f) : fmaxf(o, 0.01f * o);
    if (h == 0) {
      hout[(size_t)i * 256 + col] = o;
      hbf[(size_t)i * 256 + col] = f2bf(o);
    }
  }
}

// ---------------- pooling + heads ----------------
__device__ __forceinline__ int lbound(const int* a, int n, int v) {
  int lo = 0, hi = n;
  while (lo < hi) { int m = (lo + hi) >> 1; if (a[m] < v) lo = m + 1; else hi = m; }
  return lo;
}

__global__ void pool_kernel(const float* __restrict__ h, const int* __restrict__ batch,
                            float* __restrict__ g) {
  const int gi = blockIdx.x;
  const int t = threadIdx.x;
  int s = lbound(batch, N_NODES, gi);
  int e = lbound(batch, N_NODES, gi + 1);
  float sum = 0.f;
  for (int i = s; i < e; ++i) sum += h[(size_t)i * HIDDEN + t];
  float c = (float)(e - s);
  g[gi * HIDDEN + t] = sum / fmaxf(c, 1.f);
}

__global__ void head_kernel(const float* __restrict__ g,
                            const float* __restrict__ w1, const float* __restrict__ b1,
                            const float* __restrict__ w2, const float* __restrict__ b2,
                            float* __restrict__ out) {
  int idx = blockIdx.x * 256 + threadIdx.x;
  if (idx >= N_GRAPHS * N_OUT * 2) return;
  int which = idx >> 9;
  int rem = idx & 511;
  int row = rem >> 3, col = rem & 7;
  const float* w = which ? w2 : w1;
  float s = which ? b2[col] : b1[col];
  for (int k = 0; k < HIDDEN; ++k) s = fmaf(g[row * HIDDEN + k], w[k * N_OUT + col], s);
  out[idx] = s;
}

extern "C" void kernel_launch(void* const* d_in, const int* in_sizes, int n_in,
                              void* d_out, int out_size, void* d_ws, size_t ws_size,
                              hipStream_t stream) {
  const float* x     = (const float*)d_in[0];
  const int*   ei    = (const int*)d_in[1];
  const float* eattr = (const float*)d_in[2];
  const int*   batch = (const int*)d_in[3];
  const float* Wl1   = (const float*)d_in[4];
  const float* Wr1   = (const float*)d_in[5];
  const float* We1   = (const float*)d_in[6];
  const float* bl1   = (const float*)d_in[7];
  const float* br1   = (const float*)d_in[8];
  const float* att1  = (const float*)d_in[9];
  const float* b1    = (const float*)d_in[10];
  const float* Wls   = (const float*)d_in[11];
  const float* Wrs   = (const float*)d_in[12];
  const float* Wes   = (const float*)d_in[13];
  const float* bls   = (const float*)d_in[14];
  const float* brs   = (const float*)d_in[15];
  const float* atts  = (const float*)d_in[16];
  const float* bs    = (const float*)d_in[17];
  const float* bng   = (const float*)d_in[18];
  const float* bnb   = (const float*)d_in[19];
  const float* bnm   = (const float*)d_in[20];
  const float* bnv   = (const float*)d_in[21];
  const float* l1w   = (const float*)d_in[22];
  const float* l1b   = (const float*)d_in[23];
  const float* l2w   = (const float*)d_in[24];
  const float* l2b   = (const float*)d_in[25];
  float* out = (float*)d_out;

  char* ws = (char*)d_ws;
  auto alloc = [&](size_t bytes) {
    char* p = ws;
    ws += (bytes + 255) & ~(size_t)255;
    return p;
  };
  int*   counts   = (int*)alloc((size_t)N_NODES * 4);
  int*   offs     = (int*)alloc((size_t)(N_NODES + 1) * 4);
  int*   cursor   = (int*)alloc((size_t)N_NODES * 4);
  int*   csr_src  = (int*)alloc((size_t)N_EDGES * 4);
  unsigned short* attr_bf = (unsigned short*)alloc((size_t)N_EDGES * 16 * 2);
  unsigned short* WeTall  = (unsigned short*)alloc((size_t)5 * 256 * 16 * 2);
  float* xlr      = (float*)alloc((size_t)N_NODES * 512 * 4);
  float* hF       = (float*)alloc((size_t)N_NODES * 256 * 4);
  unsigned short* hbf0 = (unsigned short*)alloc((size_t)N_NODES * 256 * 2);
  unsigned short* hbf1 = (unsigned short*)alloc((size_t)N_NODES * 256 * 2);
  unsigned short* xbf  = (unsigned short*)alloc((size_t)N_NODES * NODE_DIM * 2);
  unsigned short* WT   = (unsigned short*)alloc((size_t)512 * 256 * 2);
  float* g        = (float*)alloc((size_t)N_GRAPHS * 256 * 4);

  hipMemsetAsync(counts, 0, (size_t)N_NODES * 4, stream);
  hist_kernel<<<(N_EDGES + 255) / 256, 256, 0, stream>>>(ei + N_EDGES, counts, N_EDGES);
  scan_kernel<<<1, 256, 0, stream>>>(counts, offs, cursor, N_NODES);
  scatter_kernel<<<(N_EDGES + 255) / 256, 256, 0, stream>>>(ei, eattr, cursor, csr_src,
                                                            attr_bf, N_EDGES);
  cvt_x<<<(N_NODES * NODE_DIM / 4 + 255) / 256, 256, 0, stream>>>(x, xbf,
                                                                  N_NODES * NODE_DIM / 4);
  cvt_we<<<5, 256, 0, stream>>>(We1, Wes, WeTall);

  for (int layer = 0; layer < 5; ++layer) {
    int K = (layer == 0) ? NODE_DIM : HIDDEN;
    const float* Wl = (layer == 0) ? Wl1 : Wls + (size_t)(layer - 1) * HIDDEN * HIDDEN;
    const float* Wr = (layer == 0) ? Wr1 : Wrs + (size_t)(layer - 1) * HIDDEN * HIDDEN;
    const float* bl = (layer == 0) ? bl1 : bls + (layer - 1) * HIDDEN;
    const float* br = (layer == 0) ? br1 : brs + (layer - 1) * HIDDEN;
    const float* at = (layer == 0) ? att1 : atts + (layer - 1) * HIDDEN;
    const float* bc = (layer == 0) ? b1 : bs + (layer - 1) * HIDDEN;
    const unsigned short* Abf = (layer == 0) ? xbf : ((layer & 1) ? hbf0 : hbf1);
    unsigned short* hbf_out = (layer & 1) ? hbf1 : hbf0;

    cvt_w<<<(512 * K + 255) / 256, 256, 0, stream>>>(Wl, Wr, WT, K);
    dim3 ggrid((N_NODES + 63) / 64, 8);
    gemm_mfma<<<ggrid, 256, 0, stream>>>(Abf, WT, bl, br, xlr, N_NODES, K);
    edge_gat<<<N_NODES / 4, 256, 0, stream>>>(
        xlr, offs, csr_src, attr_bf, WeTall + (size_t)layer * 256 * 16, at, bc,
        bng + layer * HIDDEN, bnb + layer * HIDDEN, bnm + layer * HIDDEN,
        bnv + layer * HIDDEN, hF, hbf_out, (layer == 4) ? 1 : 0);
  }
  pool_kernel<<<N_GRAPHS, 256, 0, stream>>>(hF, batch, g);
  head_kernel<<<4, 256, 0, stream>>>(g, l1w, l1b, l2w, l2b, out);
}

// Round 6
// 718.353 us; speedup vs baseline: 5.3504x; 5.3504x over previous
//
#include <hip/hip_runtime.h>

#define N_NODES 10000
#define N_EDGES 320000
#define NODE_DIM 128
#define EDGE_DIM 16
#define HIDDEN 256
#define N_OUT 8
#define N_GRAPHS 64
#define LOG2E 1.4426950408889634f

typedef float f32x2 __attribute__((ext_vector_type(2)));
typedef float f32x4 __attribute__((ext_vector_type(4)));
typedef short bf16x8 __attribute__((ext_vector_type(8)));

__device__ __forceinline__ unsigned short f2bf(float f) {
  unsigned int u = __float_as_uint(f);
  unsigned int r = (u + 0x7fff + ((u >> 16) & 1)) >> 16;
  return (unsigned short)r;
}

__device__ __forceinline__ f32x2 splat2(float v) { return (f32x2){v, v}; }

// ---------------- CSR build ----------------
__global__ void hist_kernel(const int* __restrict__ dst, int* __restrict__ counts, int E) {
  int e = blockIdx.x * blockDim.x + threadIdx.x;
  if (e < E) atomicAdd(&counts[dst[e]], 1);
}

__global__ void scan_kernel(const int* __restrict__ counts, int* __restrict__ offs,
                            int* __restrict__ cursor, int n) {
  __shared__ int part[256];
  int t = threadIdx.x;
  const int chunk = (n + 255) / 256;
  int base = t * chunk;
  int s = 0;
  for (int j = 0; j < chunk; ++j) { int i = base + j; if (i < n) s += counts[i]; }
  part[t] = s;
  __syncthreads();
  for (int off = 1; off < 256; off <<= 1) {
    int v = (t >= off) ? part[t - off] : 0;
    __syncthreads();
    part[t] += v;
    __syncthreads();
  }
  int run = (t == 0) ? 0 : part[t - 1];
  for (int j = 0; j < chunk; ++j) {
    int i = base + j;
    if (i < n) { offs[i] = run; cursor[i] = run; run += counts[i]; }
  }
  if (t == 255) offs[n] = run;
}

__global__ void scatter_kernel(const int* __restrict__ ei, const float* __restrict__ eattr,
                               int* __restrict__ cursor, int* __restrict__ csr_src,
                               float* __restrict__ csr_attr, int E) {
  int e = blockIdx.x * blockDim.x + threadIdx.x;
  if (e >= E) return;
  int s = ei[e];
  int d = ei[E + e];
  int slot = atomicAdd(&cursor[d], 1);
  csr_src[slot] = s;
  const float4* in = (const float4*)(eattr + (size_t)e * 16);
  float4* out = (float4*)(csr_attr + (size_t)slot * 16);
  out[0] = in[0]; out[1] = in[1]; out[2] = in[2]; out[3] = in[3];
}

// ---------------- weight / activation bf16 conversion ----------------
__global__ void cvt_w(const float* __restrict__ Wl, const float* __restrict__ Wr,
                      unsigned short* __restrict__ WT, int K) {
  int idx = blockIdx.x * 256 + threadIdx.x;
  if (idx >= 512 * K) return;
  int n = idx / K, k = idx - n * K;
  float v = (n < 256) ? Wl[(size_t)k * 256 + n] : Wr[(size_t)k * 256 + (n - 256)];
  WT[idx] = f2bf(v);
}

__global__ void cvt_x(const float* __restrict__ X, unsigned short* __restrict__ XB, int total4) {
  int idx = blockIdx.x * 256 + threadIdx.x;
  if (idx >= total4) return;
  float4 v = *(const float4*)(X + (size_t)idx * 4);
  ushort4 o;
  o.x = f2bf(v.x); o.y = f2bf(v.y); o.z = f2bf(v.z); o.w = f2bf(v.w);
  *(ushort4*)(XB + (size_t)idx * 4) = o;
}

// ---------------- MFMA node GEMM ----------------
__global__ __launch_bounds__(256) void gemm_mfma(
    const unsigned short* __restrict__ A,   // [M][K] bf16 row-major
    const unsigned short* __restrict__ WT,  // [512][K] bf16 (output-col major)
    const float* __restrict__ bl, const float* __restrict__ br,
    float* __restrict__ C, int M, int K) {
  const int t = threadIdx.x;
  const int wv = t >> 6;
  const int l = t & 63;
  const int bm = blockIdx.x * 64;
  const int bn = blockIdx.y * 64;
  const int col = bn + wv * 16 + (l & 15);
  const int kgrp = (l >> 4) * 8;
  f32x4 acc[4];
#pragma unroll
  for (int mt = 0; mt < 4; ++mt) acc[mt] = (f32x4){0.f, 0.f, 0.f, 0.f};

  int arow[4];
#pragma unroll
  for (int mt = 0; mt < 4; ++mt) {
    int r = bm + mt * 16 + (l & 15);
    arow[mt] = (r < M) ? r : M - 1;
  }

  for (int k0 = 0; k0 < K; k0 += 32) {
    bf16x8 bfrag = *(const bf16x8*)(WT + (size_t)col * K + k0 + kgrp);
#pragma unroll
    for (int mt = 0; mt < 4; ++mt) {
      bf16x8 afrag = *(const bf16x8*)(A + (size_t)arow[mt] * K + k0 + kgrp);
      acc[mt] = __builtin_amdgcn_mfma_f32_16x16x32_bf16(afrag, bfrag, acc[mt], 0, 0, 0);
    }
  }
  const float bias = (col < 256) ? bl[col] : br[col - 256];
#pragma unroll
  for (int mt = 0; mt < 4; ++mt) {
#pragma unroll
    for (int j = 0; j < 4; ++j) {
      int row = bm + mt * 16 + (l >> 4) * 4 + j;
      if (row < M) C[(size_t)row * 512 + col] = acc[mt][j] + bias;
    }
  }
}

// ---------------- fused edge scoring + segment softmax + aggregate + BN + act ----------------
// Wave per dst node (4/block); We staged in LDS (16KB, shared by the block's 4 waves);
// 4 edges per iteration with d-loop OUTER so each ds_read_b128 of We serves all 4
// edges; column math packed f32x2 via __builtin_elementwise_fma (v_pk_fma_f32,
// compiler-scheduled). Online softmax identical to the proven R2 version.
__global__ __launch_bounds__(256, 4) void edge_gat(
    const float* __restrict__ xlr,
    const int* __restrict__ offs, const int* __restrict__ csr_src,
    const float* __restrict__ csr_attr,
    const float* __restrict__ We, const float* __restrict__ att,
    const float* __restrict__ bconv,
    const float* __restrict__ gamma, const float* __restrict__ beta,
    const float* __restrict__ mean, const float* __restrict__ var,
    float* __restrict__ hout, unsigned short* __restrict__ hbf, int relu_last) {
  __shared__ float We_lds[EDGE_DIM * HIDDEN];
  {
    const float4* src = (const float4*)We;
    float4* dst = (float4*)We_lds;
#pragma unroll
    for (int j = 0; j < 4; ++j)
      dst[threadIdx.x + j * 256] = src[threadIdx.x + j * 256];
  }
  __syncthreads();

  const int t = threadIdx.x;
  const int w = t >> 6;
  const int l = t & 63;
  const int h4 = l << 2;
  const int iu = __builtin_amdgcn_readfirstlane(blockIdx.x * 4 + w);

  const float4 att4 = *(const float4*)(att + h4);
  const f32x2 attA = {att4.x * LOG2E, att4.y * LOG2E};
  const f32x2 attB = {att4.z * LOG2E, att4.w * LOG2E};
  const float4 xr4 = *(const float4*)(xlr + (size_t)iu * 512 + HIDDEN + h4);
  const f32x2 xrA = {xr4.x, xr4.y};
  const f32x2 xrB = {xr4.z, xr4.w};

  const int rs = __builtin_amdgcn_readfirstlane(offs[iu]);
  const int re = __builtin_amdgcn_readfirstlane(offs[iu + 1]);

  float mrun = -1e30f, den = 0.f;
  f32x2 outA = {0.f, 0.f}, outB = {0.f, 0.f};

  for (int e = rs; e < re; e += 4) {
    const int e0 = e;
    const int e1 = (e + 1 < re) ? e + 1 : e;
    const int e2 = (e + 2 < re) ? e + 2 : e;
    const int e3 = (e + 3 < re) ? e + 3 : e;
    const int s0 = __builtin_amdgcn_readfirstlane(csr_src[e0]);
    const int s1 = __builtin_amdgcn_readfirstlane(csr_src[e1]);
    const int s2 = __builtin_amdgcn_readfirstlane(csr_src[e2]);
    const int s3 = __builtin_amdgcn_readfirstlane(csr_src[e3]);
    const float4 xl0 = *(const float4*)(xlr + (size_t)s0 * 512 + h4);
    const float4 xl1 = *(const float4*)(xlr + (size_t)s1 * 512 + h4);
    const float4 xl2 = *(const float4*)(xlr + (size_t)s2 * 512 + h4);
    const float4 xl3 = *(const float4*)(xlr + (size_t)s3 * 512 + h4);
    const f32x2 xlA0 = {xl0.x, xl0.y}, xlB0 = {xl0.z, xl0.w};
    const f32x2 xlA1 = {xl1.x, xl1.y}, xlB1 = {xl1.z, xl1.w};
    const f32x2 xlA2 = {xl2.x, xl2.y}, xlB2 = {xl2.z, xl2.w};
    const f32x2 xlA3 = {xl3.x, xl3.y}, xlB3 = {xl3.z, xl3.w};

    const float* a0 = csr_attr + (size_t)e0 * 16;
    const float* a1 = csr_attr + (size_t)e1 * 16;
    const float* a2 = csr_attr + (size_t)e2 * 16;
    const float* a3 = csr_attr + (size_t)e3 * 16;

    f32x2 zA0 = xrA + xlA0, zB0 = xrB + xlB0;
    f32x2 zA1 = xrA + xlA1, zB1 = xrB + xlB1;
    f32x2 zA2 = xrA + xlA2, zB2 = xrB + xlB2;
    f32x2 zA3 = xrA + xlA3, zB3 = xrB + xlB3;

#pragma unroll
    for (int d = 0; d < 16; ++d) {
      const f32x4 w4 = *(const f32x4*)(We_lds + d * HIDDEN + h4);
      const f32x2 wA = __builtin_shufflevector(w4, w4, 0, 1);
      const f32x2 wB = __builtin_shufflevector(w4, w4, 2, 3);
      zA0 = __builtin_elementwise_fma(splat2(a0[d]), wA, zA0);
      zB0 = __builtin_elementwise_fma(splat2(a0[d]), wB, zB0);
      zA1 = __builtin_elementwise_fma(splat2(a1[d]), wA, zA1);
      zB1 = __builtin_elementwise_fma(splat2(a1[d]), wB, zB1);
      zA2 = __builtin_elementwise_fma(splat2(a2[d]), wA, zA2);
      zB2 = __builtin_elementwise_fma(splat2(a2[d]), wB, zB2);
      zA3 = __builtin_elementwise_fma(splat2(a3[d]), wA, zA3);
      zB3 = __builtin_elementwise_fma(splat2(a3[d]), wB, zB3);
    }

    // leaky_relu(z, 0.2) then dot with att (pairs), horizontal add
    zA0 = __builtin_elementwise_max(zA0, 0.2f * zA0);
    zB0 = __builtin_elementwise_max(zB0, 0.2f * zB0);
    zA1 = __builtin_elementwise_max(zA1, 0.2f * zA1);
    zB1 = __builtin_elementwise_max(zB1, 0.2f * zB1);
    zA2 = __builtin_elementwise_max(zA2, 0.2f * zA2);
    zB2 = __builtin_elementwise_max(zB2, 0.2f * zB2);
    zA3 = __builtin_elementwise_max(zA3, 0.2f * zA3);
    zB3 = __builtin_elementwise_max(zB3, 0.2f * zB3);
    f32x2 dp0 = __builtin_elementwise_fma(attB, zB0, attA * zA0);
    f32x2 dp1 = __builtin_elementwise_fma(attB, zB1, attA * zA1);
    f32x2 dp2 = __builtin_elementwise_fma(attB, zB2, attA * zA2);
    f32x2 dp3 = __builtin_elementwise_fma(attB, zB3, attA * zA3);
    float p0 = dp0.x + dp0.y;
    float p1 = dp1.x + dp1.y;
    float p2 = dp2.x + dp2.y;
    float p3 = dp3.x + dp3.y;

#pragma unroll
    for (int off = 32; off > 0; off >>= 1) {
      p0 += __shfl_xor(p0, off, 64);
      p1 += __shfl_xor(p1, off, 64);
      p2 += __shfl_xor(p2, off, 64);
      p3 += __shfl_xor(p3, off, 64);
    }
    if (e + 1 >= re) p1 = -1e30f;
    if (e + 2 >= re) p2 = -1e30f;
    if (e + 3 >= re) p3 = -1e30f;

    const float bmx = fmaxf(fmaxf(p0, p1), fmaxf(p2, p3));
    const float nm = fmaxf(mrun, bmx);
    const float sc = exp2f(mrun - nm);
    const float w0 = exp2f(p0 - nm);
    const float w1 = exp2f(p1 - nm);
    const float w2 = exp2f(p2 - nm);
    const float w3 = exp2f(p3 - nm);
    den = fmaf(den, sc, (w0 + w1) + (w2 + w3));
    f32x2 tA = splat2(w0) * xlA0;
    tA = __builtin_elementwise_fma(splat2(w1), xlA1, tA);
    tA = __builtin_elementwise_fma(splat2(w2), xlA2, tA);
    tA = __builtin_elementwise_fma(splat2(w3), xlA3, tA);
    f32x2 tB = splat2(w0) * xlB0;
    tB = __builtin_elementwise_fma(splat2(w1), xlB1, tB);
    tB = __builtin_elementwise_fma(splat2(w2), xlB2, tB);
    tB = __builtin_elementwise_fma(splat2(w3), xlB3, tB);
    outA = __builtin_elementwise_fma(outA, splat2(sc), tA);
    outB = __builtin_elementwise_fma(outB, splat2(sc), tB);
    mrun = nm;
  }

  const float inv = (den > 0.f) ? __frcp_rn(den) : 0.f;
  const float4 bc4 = *(const float4*)(bconv + h4);
  const float4 g4 = *(const float4*)(gamma + h4);
  const float4 b4 = *(const float4*)(beta + h4);
  const float4 m4 = *(const float4*)(mean + h4);
  const float4 v4 = *(const float4*)(var + h4);
  float o[4] = {outA.x, outA.y, outB.x, outB.y};
  const float bc[4] = {bc4.x, bc4.y, bc4.z, bc4.w};
  const float gm[4] = {g4.x, g4.y, g4.z, g4.w};
  const float bt[4] = {b4.x, b4.y, b4.z, b4.w};
  const float mn[4] = {m4.x, m4.y, m4.z, m4.w};
  const float vr[4] = {v4.x, v4.y, v4.z, v4.w};
  float4 res;
  float* rp = (float*)&res;
#pragma unroll
  for (int j = 0; j < 4; ++j) {
    float y = fmaf(o[j], inv, bc[j]);
    y = (y - mn[j]) * rsqrtf(vr[j] + 1e-5f) * gm[j] + bt[j];
    rp[j] = relu_last ? fmaxf(y, 0.f) : fmaxf(y, 0.01f * y);
  }
  *(float4*)(hout + (size_t)iu * HIDDEN + h4) = res;
  ushort4 rb;
  rb.x = f2bf(rp[0]); rb.y = f2bf(rp[1]); rb.z = f2bf(rp[2]); rb.w = f2bf(rp[3]);
  *(ushort4*)(hbf + (size_t)iu * HIDDEN + h4) = rb;
}

// ---------------- pooling + heads ----------------
__device__ __forceinline__ int lbound(const int* a, int n, int v) {
  int lo = 0, hi = n;
  while (lo < hi) { int m = (lo + hi) >> 1; if (a[m] < v) lo = m + 1; else hi = m; }
  return lo;
}

__global__ void pool_kernel(const float* __restrict__ h, const int* __restrict__ batch,
                            float* __restrict__ g) {
  const int gi = blockIdx.x;
  const int t = threadIdx.x;
  int s = lbound(batch, N_NODES, gi);
  int e = lbound(batch, N_NODES, gi + 1);
  float sum = 0.f;
  for (int i = s; i < e; ++i) sum += h[(size_t)i * HIDDEN + t];
  float c = (float)(e - s);
  g[gi * HIDDEN + t] = sum / fmaxf(c, 1.f);
}

__global__ void head_kernel(const float* __restrict__ g,
                            const float* __restrict__ w1, const float* __restrict__ b1,
                            const float* __restrict__ w2, const float* __restrict__ b2,
                            float* __restrict__ out) {
  int idx = blockIdx.x * 256 + threadIdx.x;
  if (idx >= N_GRAPHS * N_OUT * 2) return;
  int which = idx >> 9;
  int rem = idx & 511;
  int row = rem >> 3, col = rem & 7;
  const float* w = which ? w2 : w1;
  float s = which ? b2[col] : b1[col];
  for (int k = 0; k < HIDDEN; ++k) s = fmaf(g[row * HIDDEN + k], w[k * N_OUT + col], s);
  out[idx] = s;
}

extern "C" void kernel_launch(void* const* d_in, const int* in_sizes, int n_in,
                              void* d_out, int out_size, void* d_ws, size_t ws_size,
                              hipStream_t stream) {
  const float* x     = (const float*)d_in[0];
  const int*   ei    = (const int*)d_in[1];
  const float* eattr = (const float*)d_in[2];
  const int*   batch = (const int*)d_in[3];
  const float* Wl1   = (const float*)d_in[4];
  const float* Wr1   = (const float*)d_in[5];
  const float* We1   = (const float*)d_in[6];
  const float* bl1   = (const float*)d_in[7];
  const float* br1   = (const float*)d_in[8];
  const float* att1  = (const float*)d_in[9];
  const float* b1    = (const float*)d_in[10];
  const float* Wls   = (const float*)d_in[11];
  const float* Wrs   = (const float*)d_in[12];
  const float* Wes   = (const float*)d_in[13];
  const float* bls   = (const float*)d_in[14];
  const float* brs   = (const float*)d_in[15];
  const float* atts  = (const float*)d_in[16];
  const float* bs    = (const float*)d_in[17];
  const float* bng   = (const float*)d_in[18];
  const float* bnb   = (const float*)d_in[19];
  const float* bnm   = (const float*)d_in[20];
  const float* bnv   = (const float*)d_in[21];
  const float* l1w   = (const float*)d_in[22];
  const float* l1b   = (const float*)d_in[23];
  const float* l2w   = (const float*)d_in[24];
  const float* l2b   = (const float*)d_in[25];
  float* out = (float*)d_out;

  char* ws = (char*)d_ws;
  auto alloc = [&](size_t bytes) {
    char* p = ws;
    ws += (bytes + 255) & ~(size_t)255;
    return p;
  };
  int*   counts   = (int*)alloc((size_t)N_NODES * 4);
  int*   offs     = (int*)alloc((size_t)(N_NODES + 1) * 4);
  int*   cursor   = (int*)alloc((size_t)N_NODES * 4);
  int*   csr_src  = (int*)alloc((size_t)N_EDGES * 4);
  float* csr_attr = (float*)alloc((size_t)N_EDGES * 16 * 4);
  float* xlr      = (float*)alloc((size_t)N_NODES * 512 * 4);
  float* hF       = (float*)alloc((size_t)N_NODES * 256 * 4);
  unsigned short* hbf0 = (unsigned short*)alloc((size_t)N_NODES * 256 * 2);
  unsigned short* hbf1 = (unsigned short*)alloc((size_t)N_NODES * 256 * 2);
  unsigned short* xbf  = (unsigned short*)alloc((size_t)N_NODES * NODE_DIM * 2);
  unsigned short* WT   = (unsigned short*)alloc((size_t)512 * 256 * 2);
  float* g        = (float*)alloc((size_t)N_GRAPHS * 256 * 4);

  hipMemsetAsync(counts, 0, (size_t)N_NODES * 4, stream);
  hist_kernel<<<(N_EDGES + 255) / 256, 256, 0, stream>>>(ei + N_EDGES, counts, N_EDGES);
  scan_kernel<<<1, 256, 0, stream>>>(counts, offs, cursor, N_NODES);
  scatter_kernel<<<(N_EDGES + 255) / 256, 256, 0, stream>>>(ei, eattr, cursor, csr_src,
                                                            csr_attr, N_EDGES);
  cvt_x<<<(N_NODES * NODE_DIM / 4 + 255) / 256, 256, 0, stream>>>(x, xbf,
                                                                  N_NODES * NODE_DIM / 4);

  for (int layer = 0; layer < 5; ++layer) {
    int K = (layer == 0) ? NODE_DIM : HIDDEN;
    const float* Wl = (layer == 0) ? Wl1 : Wls + (size_t)(layer - 1) * HIDDEN * HIDDEN;
    const float* Wr = (layer == 0) ? Wr1 : Wrs + (size_t)(layer - 1) * HIDDEN * HIDDEN;
    const float* We = (layer == 0) ? We1 : Wes + (size_t)(layer - 1) * EDGE_DIM * HIDDEN;
    const float* bl = (layer == 0) ? bl1 : bls + (layer - 1) * HIDDEN;
    const float* br = (layer == 0) ? br1 : brs + (layer - 1) * HIDDEN;
    const float* at = (layer == 0) ? att1 : atts + (layer - 1) * HIDDEN;
    const float* bc = (layer == 0) ? b1 : bs + (layer - 1) * HIDDEN;
    const unsigned short* Abf = (layer == 0) ? xbf : ((layer & 1) ? hbf0 : hbf1);
    unsigned short* hbf_out = (layer & 1) ? hbf1 : hbf0;

    cvt_w<<<(512 * K + 255) / 256, 256, 0, stream>>>(Wl, Wr, WT, K);
    dim3 ggrid((N_NODES + 63) / 64, 8);
    gemm_mfma<<<ggrid, 256, 0, stream>>>(Abf, WT, bl, br, xlr, N_NODES, K);
    edge_gat<<<N_NODES / 4, 256, 0, stream>>>(xlr, offs, csr_src, csr_attr, We, at, bc,
                                              bng + layer * HIDDEN, bnb + layer * HIDDEN,
                                              bnm + layer * HIDDEN, bnv + layer * HIDDEN,
                                              hF, hbf_out, (layer == 4) ? 1 : 0);
  }
  pool_kernel<<<N_GRAPHS, 256, 0, stream>>>(hF, batch, g);
  head_kernel<<<4, 256, 0, stream>>>(g, l1w, l1b, l2w, l2b, out);
}

// Round 7
// 641.809 us; speedup vs baseline: 5.9885x; 1.1193x over previous
//
#include <hip/hip_runtime.h>

#define N_NODES 10000
#define N_EDGES 320000
#define NODE_DIM 128
#define EDGE_DIM 16
#define HIDDEN 256
#define N_OUT 8
#define N_GRAPHS 64
#define LOG2E 1.4426950408889634f

typedef float f32x4 __attribute__((ext_vector_type(4)));
typedef short bf16x8 __attribute__((ext_vector_type(8)));

__device__ __forceinline__ unsigned short f2bf(float f) {
  unsigned int u = __float_as_uint(f);
  unsigned int r = (u + 0x7fff + ((u >> 16) & 1)) >> 16;
  return (unsigned short)r;
}

// ---------------- CSR build ----------------
__global__ void hist_kernel(const int* __restrict__ dst, int* __restrict__ counts, int E) {
  int e = blockIdx.x * blockDim.x + threadIdx.x;
  if (e < E) atomicAdd(&counts[dst[e]], 1);
}

__global__ void scan_kernel(const int* __restrict__ counts, int* __restrict__ offs,
                            int* __restrict__ cursor, int n) {
  __shared__ int part[256];
  int t = threadIdx.x;
  const int chunk = (n + 255) / 256;
  int base = t * chunk;
  int s = 0;
  for (int j = 0; j < chunk; ++j) { int i = base + j; if (i < n) s += counts[i]; }
  part[t] = s;
  __syncthreads();
  for (int off = 1; off < 256; off <<= 1) {
    int v = (t >= off) ? part[t - off] : 0;
    __syncthreads();
    part[t] += v;
    __syncthreads();
  }
  int run = (t == 0) ? 0 : part[t - 1];
  for (int j = 0; j < chunk; ++j) {
    int i = base + j;
    if (i < n) { offs[i] = run; cursor[i] = run; run += counts[i]; }
  }
  if (t == 255) offs[n] = run;
}

__global__ void scatter_kernel(const int* __restrict__ ei, const float* __restrict__ eattr,
                               int* __restrict__ cursor, int* __restrict__ csr_src,
                               float* __restrict__ csr_attr, int E) {
  int e = blockIdx.x * blockDim.x + threadIdx.x;
  if (e >= E) return;
  int s = ei[e];
  int d = ei[E + e];
  int slot = atomicAdd(&cursor[d], 1);
  csr_src[slot] = s;
  const float4* in = (const float4*)(eattr + (size_t)e * 16);
  float4* out = (float4*)(csr_attr + (size_t)slot * 16);
  out[0] = in[0]; out[1] = in[1]; out[2] = in[2]; out[3] = in[3];
}

// ---------------- weight / activation bf16 conversion (all 5 layers upfront) ----------------
// WTall[layer][n][k] bf16, n in [0,512): n<256 -> Wl[k][n], else Wr[k][n-256]. Layer0 K=128.
__global__ void cvt_w_all(const float* __restrict__ Wl1, const float* __restrict__ Wr1,
                          const float* __restrict__ Wls, const float* __restrict__ Wrs,
                          unsigned short* __restrict__ WTall) {
  const int layer = blockIdx.y;
  const int K = (layer == 0) ? NODE_DIM : HIDDEN;
  int idx = blockIdx.x * 256 + threadIdx.x;
  if (idx >= 512 * K) return;
  int n = idx / K, k = idx - n * K;
  const float* Wl = (layer == 0) ? Wl1 : Wls + (size_t)(layer - 1) * HIDDEN * HIDDEN;
  const float* Wr = (layer == 0) ? Wr1 : Wrs + (size_t)(layer - 1) * HIDDEN * HIDDEN;
  float v = (n < 256) ? Wl[(size_t)k * 256 + n] : Wr[(size_t)k * 256 + (n - 256)];
  WTall[(size_t)layer * 512 * 256 + idx] = f2bf(v);
}

__global__ void cvt_x(const float* __restrict__ X, unsigned short* __restrict__ XB, int total4) {
  int idx = blockIdx.x * 256 + threadIdx.x;
  if (idx >= total4) return;
  float4 v = *(const float4*)(X + (size_t)idx * 4);
  ushort4 o;
  o.x = f2bf(v.x); o.y = f2bf(v.y); o.z = f2bf(v.z); o.w = f2bf(v.w);
  *(ushort4*)(XB + (size_t)idx * 4) = o;
}

// ---------------- MFMA node GEMM ----------------
__global__ __launch_bounds__(256) void gemm_mfma(
    const unsigned short* __restrict__ A,   // [M][K] bf16 row-major
    const unsigned short* __restrict__ WT,  // [512][K] bf16 (output-col major)
    const float* __restrict__ bl, const float* __restrict__ br,
    float* __restrict__ C, int M, int K) {
  const int t = threadIdx.x;
  const int wv = t >> 6;
  const int l = t & 63;
  const int bm = blockIdx.x * 64;
  const int bn = blockIdx.y * 64;
  const int col = bn + wv * 16 + (l & 15);
  const int kgrp = (l >> 4) * 8;
  f32x4 acc[4];
#pragma unroll
  for (int mt = 0; mt < 4; ++mt) acc[mt] = (f32x4){0.f, 0.f, 0.f, 0.f};

  int arow[4];
#pragma unroll
  for (int mt = 0; mt < 4; ++mt) {
    int r = bm + mt * 16 + (l & 15);
    arow[mt] = (r < M) ? r : M - 1;
  }

  for (int k0 = 0; k0 < K; k0 += 32) {
    bf16x8 bfrag = *(const bf16x8*)(WT + (size_t)col * K + k0 + kgrp);
#pragma unroll
    for (int mt = 0; mt < 4; ++mt) {
      bf16x8 afrag = *(const bf16x8*)(A + (size_t)arow[mt] * K + k0 + kgrp);
      acc[mt] = __builtin_amdgcn_mfma_f32_16x16x32_bf16(afrag, bfrag, acc[mt], 0, 0, 0);
    }
  }
  const float bias = (col < 256) ? bl[col] : br[col - 256];
#pragma unroll
  for (int mt = 0; mt < 4; ++mt) {
#pragma unroll
    for (int j = 0; j < 4; ++j) {
      int row = bm + mt * 16 + (l >> 4) * 4 + j;
      if (row < M) C[(size_t)row * 512 + col] = acc[mt][j] + bias;
    }
  }
}

// ---------------- fused edge scoring + segment softmax + aggregate + BN + act ----------------
// Wave per dst node (4/block). 4 edges/iter; d-loop OUTER so each VMEM float4 read
// of We (L1-hot, vmcnt-pipelined) serves 4 edges. z init = xr only; xl added AFTER
// the d-loop so the 4 gather loads overlap the 256-FMA block. attr via s_load
// (wave-uniform). Online softmax as proven in R2.
__global__ __launch_bounds__(256, 4) void edge_gat(
    const float* __restrict__ xlr,
    const int* __restrict__ offs, const int* __restrict__ csr_src,
    const float* __restrict__ csr_attr,
    const float* __restrict__ We, const float* __restrict__ att,
    const float* __restrict__ bconv,
    const float* __restrict__ gamma, const float* __restrict__ beta,
    const float* __restrict__ mean, const float* __restrict__ var,
    float* __restrict__ hout, unsigned short* __restrict__ hbf, int relu_last) {
  const int t = threadIdx.x;
  const int w = t >> 6;
  const int l = t & 63;
  const int h4 = l << 2;
  const int iu = __builtin_amdgcn_readfirstlane(blockIdx.x * 4 + w);

  float4 att4 = *(const float4*)(att + h4);
  att4.x *= LOG2E; att4.y *= LOG2E; att4.z *= LOG2E; att4.w *= LOG2E;
  const float4 xr4 = *(const float4*)(xlr + (size_t)iu * 512 + HIDDEN + h4);

  const int rs = __builtin_amdgcn_readfirstlane(offs[iu]);
  const int re = __builtin_amdgcn_readfirstlane(offs[iu + 1]);

  float mrun = -1e30f, den = 0.f;
  float4 acc = make_float4(0.f, 0.f, 0.f, 0.f);

  for (int e = rs; e < re; e += 4) {
    const int e0 = e;
    const int e1 = (e + 1 < re) ? e + 1 : e;
    const int e2 = (e + 2 < re) ? e + 2 : e;
    const int e3 = (e + 3 < re) ? e + 3 : e;
    const int s0 = __builtin_amdgcn_readfirstlane(csr_src[e0]);
    const int s1 = __builtin_amdgcn_readfirstlane(csr_src[e1]);
    const int s2 = __builtin_amdgcn_readfirstlane(csr_src[e2]);
    const int s3 = __builtin_amdgcn_readfirstlane(csr_src[e3]);
    const float4 xl0 = *(const float4*)(xlr + (size_t)s0 * 512 + h4);
    const float4 xl1 = *(const float4*)(xlr + (size_t)s1 * 512 + h4);
    const float4 xl2 = *(const float4*)(xlr + (size_t)s2 * 512 + h4);
    const float4 xl3 = *(const float4*)(xlr + (size_t)s3 * 512 + h4);

    const float* a0 = csr_attr + (size_t)e0 * 16;
    const float* a1 = csr_attr + (size_t)e1 * 16;
    const float* a2 = csr_attr + (size_t)e2 * 16;
    const float* a3 = csr_attr + (size_t)e3 * 16;

    // ew accumulators, init from xr (no load dependency)
    float z0x = xr4.x, z0y = xr4.y, z0z = xr4.z, z0w = xr4.w;
    float z1x = xr4.x, z1y = xr4.y, z1z = xr4.z, z1w = xr4.w;
    float z2x = xr4.x, z2y = xr4.y, z2z = xr4.z, z2w = xr4.w;
    float z3x = xr4.x, z3y = xr4.y, z3z = xr4.z, z3w = xr4.w;

#pragma unroll
    for (int d = 0; d < 16; ++d) {
      const float4 w4 = *(const float4*)(We + d * HIDDEN + h4);
      const float c0 = a0[d], c1 = a1[d], c2 = a2[d], c3 = a3[d];
      z0x = fmaf(c0, w4.x, z0x); z0y = fmaf(c0, w4.y, z0y);
      z0z = fmaf(c0, w4.z, z0z); z0w = fmaf(c0, w4.w, z0w);
      z1x = fmaf(c1, w4.x, z1x); z1y = fmaf(c1, w4.y, z1y);
      z1z = fmaf(c1, w4.z, z1z); z1w = fmaf(c1, w4.w, z1w);
      z2x = fmaf(c2, w4.x, z2x); z2y = fmaf(c2, w4.y, z2y);
      z2z = fmaf(c2, w4.z, z2z); z2w = fmaf(c2, w4.w, z2w);
      z3x = fmaf(c3, w4.x, z3x); z3y = fmaf(c3, w4.y, z3y);
      z3z = fmaf(c3, w4.z, z3z); z3w = fmaf(c3, w4.w, z3w);
    }

    // add xl (loads issued at iter start, consumed here), leaky, dot with att
    float p0, p1, p2, p3;
    {
      float zx, zy, zz, zw;
      zx = z0x + xl0.x; zy = z0y + xl0.y; zz = z0z + xl0.z; zw = z0w + xl0.w;
      zx = fmaxf(zx, 0.2f * zx); zy = fmaxf(zy, 0.2f * zy);
      zz = fmaxf(zz, 0.2f * zz); zw = fmaxf(zw, 0.2f * zw);
      p0 = att4.x * zx; p0 = fmaf(att4.y, zy, p0); p0 = fmaf(att4.z, zz, p0); p0 = fmaf(att4.w, zw, p0);
      zx = z1x + xl1.x; zy = z1y + xl1.y; zz = z1z + xl1.z; zw = z1w + xl1.w;
      zx = fmaxf(zx, 0.2f * zx); zy = fmaxf(zy, 0.2f * zy);
      zz = fmaxf(zz, 0.2f * zz); zw = fmaxf(zw, 0.2f * zw);
      p1 = att4.x * zx; p1 = fmaf(att4.y, zy, p1); p1 = fmaf(att4.z, zz, p1); p1 = fmaf(att4.w, zw, p1);
      zx = z2x + xl2.x; zy = z2y + xl2.y; zz = z2z + xl2.z; zw = z2w + xl2.w;
      zx = fmaxf(zx, 0.2f * zx); zy = fmaxf(zy, 0.2f * zy);
      zz = fmaxf(zz, 0.2f * zz); zw = fmaxf(zw, 0.2f * zw);
      p2 = att4.x * zx; p2 = fmaf(att4.y, zy, p2); p2 = fmaf(att4.z, zz, p2); p2 = fmaf(att4.w, zw, p2);
      zx = z3x + xl3.x; zy = z3y + xl3.y; zz = z3z + xl3.z; zw = z3w + xl3.w;
      zx = fmaxf(zx, 0.2f * zx); zy = fmaxf(zy, 0.2f * zy);
      zz = fmaxf(zz, 0.2f * zz); zw = fmaxf(zw, 0.2f * zw);
      p3 = att4.x * zx; p3 = fmaf(att4.y, zy, p3); p3 = fmaf(att4.z, zz, p3); p3 = fmaf(att4.w, zw, p3);
    }

#pragma unroll
    for (int off = 32; off > 0; off >>= 1) {
      p0 += __shfl_xor(p0, off, 64);
      p1 += __shfl_xor(p1, off, 64);
      p2 += __shfl_xor(p2, off, 64);
      p3 += __shfl_xor(p3, off, 64);
    }
    if (e + 1 >= re) p1 = -1e30f;
    if (e + 2 >= re) p2 = -1e30f;
    if (e + 3 >= re) p3 = -1e30f;

    const float bmx = fmaxf(fmaxf(p0, p1), fmaxf(p2, p3));
    const float nm = fmaxf(mrun, bmx);
    const float sc = exp2f(mrun - nm);
    const float w0 = exp2f(p0 - nm);
    const float w1 = exp2f(p1 - nm);
    const float w2 = exp2f(p2 - nm);
    const float w3 = exp2f(p3 - nm);
    den = fmaf(den, sc, (w0 + w1) + (w2 + w3));
    float tx = w0 * xl0.x; tx = fmaf(w1, xl1.x, tx); tx = fmaf(w2, xl2.x, tx); tx = fmaf(w3, xl3.x, tx);
    float ty = w0 * xl0.y; ty = fmaf(w1, xl1.y, ty); ty = fmaf(w2, xl2.y, ty); ty = fmaf(w3, xl3.y, ty);
    float tz = w0 * xl0.z; tz = fmaf(w1, xl1.z, tz); tz = fmaf(w2, xl2.z, tz); tz = fmaf(w3, xl3.z, tz);
    float tw = w0 * xl0.w; tw = fmaf(w1, xl1.w, tw); tw = fmaf(w2, xl2.w, tw); tw = fmaf(w3, xl3.w, tw);
    acc.x = fmaf(acc.x, sc, tx);
    acc.y = fmaf(acc.y, sc, ty);
    acc.z = fmaf(acc.z, sc, tz);
    acc.w = fmaf(acc.w, sc, tw);
    mrun = nm;
  }

  const float inv = (den > 0.f) ? __frcp_rn(den) : 0.f;
  const float4 bc4 = *(const float4*)(bconv + h4);
  const float4 g4 = *(const float4*)(gamma + h4);
  const float4 b4 = *(const float4*)(beta + h4);
  const float4 m4 = *(const float4*)(mean + h4);
  const float4 v4 = *(const float4*)(var + h4);
  float o[4] = {acc.x, acc.y, acc.z, acc.w};
  const float bc[4] = {bc4.x, bc4.y, bc4.z, bc4.w};
  const float gm[4] = {g4.x, g4.y, g4.z, g4.w};
  const float bt[4] = {b4.x, b4.y, b4.z, b4.w};
  const float mn[4] = {m4.x, m4.y, m4.z, m4.w};
  const float vr[4] = {v4.x, v4.y, v4.z, v4.w};
  float res[4];
#pragma unroll
  for (int j = 0; j < 4; ++j) {
    float y = fmaf(o[j], inv, bc[j]);
    y = (y - mn[j]) * rsqrtf(vr[j] + 1e-5f) * gm[j] + bt[j];
    res[j] = relu_last ? fmaxf(y, 0.f) : fmaxf(y, 0.01f * y);
  }
  if (relu_last) {
    float4 rf = {res[0], res[1], res[2], res[3]};
    *(float4*)(hout + (size_t)iu * HIDDEN + h4) = rf;
  }
  ushort4 rb;
  rb.x = f2bf(res[0]); rb.y = f2bf(res[1]); rb.z = f2bf(res[2]); rb.w = f2bf(res[3]);
  *(ushort4*)(hbf + (size_t)iu * HIDDEN + h4) = rb;
}

// ---------------- pooling + heads ----------------
__device__ __forceinline__ int lbound(const int* a, int n, int v) {
  int lo = 0, hi = n;
  while (lo < hi) { int m = (lo + hi) >> 1; if (a[m] < v) lo = m + 1; else hi = m; }
  return lo;
}

__global__ void pool_kernel(const float* __restrict__ h, const int* __restrict__ batch,
                            float* __restrict__ g) {
  const int gi = blockIdx.x;
  const int t = threadIdx.x;
  int s = lbound(batch, N_NODES, gi);
  int e = lbound(batch, N_NODES, gi + 1);
  float sum = 0.f;
  for (int i = s; i < e; ++i) sum += h[(size_t)i * HIDDEN + t];
  float c = (float)(e - s);
  g[gi * HIDDEN + t] = sum / fmaxf(c, 1.f);
}

__global__ void head_kernel(const float* __restrict__ g,
                            const float* __restrict__ w1, const float* __restrict__ b1,
                            const float* __restrict__ w2, const float* __restrict__ b2,
                            float* __restrict__ out) {
  int idx = blockIdx.x * 256 + threadIdx.x;
  if (idx >= N_GRAPHS * N_OUT * 2) return;
  int which = idx >> 9;
  int rem = idx & 511;
  int row = rem >> 3, col = rem & 7;
  const float* w = which ? w2 : w1;
  float s = which ? b2[col] : b1[col];
  for (int k = 0; k < HIDDEN; ++k) s = fmaf(g[row * HIDDEN + k], w[k * N_OUT + col], s);
  out[idx] = s;
}

extern "C" void kernel_launch(void* const* d_in, const int* in_sizes, int n_in,
                              void* d_out, int out_size, void* d_ws, size_t ws_size,
                              hipStream_t stream) {
  const float* x     = (const float*)d_in[0];
  const int*   ei    = (const int*)d_in[1];
  const float* eattr = (const float*)d_in[2];
  const int*   batch = (const int*)d_in[3];
  const float* Wl1   = (const float*)d_in[4];
  const float* Wr1   = (const float*)d_in[5];
  const float* We1   = (const float*)d_in[6];
  const float* bl1   = (const float*)d_in[7];
  const float* br1   = (const float*)d_in[8];
  const float* att1  = (const float*)d_in[9];
  const float* b1    = (const float*)d_in[10];
  const float* Wls   = (const float*)d_in[11];
  const float* Wrs   = (const float*)d_in[12];
  const float* Wes   = (const float*)d_in[13];
  const float* bls   = (const float*)d_in[14];
  const float* brs   = (const float*)d_in[15];
  const float* atts  = (const float*)d_in[16];
  const float* bs    = (const float*)d_in[17];
  const float* bng   = (const float*)d_in[18];
  const float* bnb   = (const float*)d_in[19];
  const float* bnm   = (const float*)d_in[20];
  const float* bnv   = (const float*)d_in[21];
  const float* l1w   = (const float*)d_in[22];
  const float* l1b   = (const float*)d_in[23];
  const float* l2w   = (const float*)d_in[24];
  const float* l2b   = (const float*)d_in[25];
  float* out = (float*)d_out;

  char* ws = (char*)d_ws;
  auto alloc = [&](size_t bytes) {
    char* p = ws;
    ws += (bytes + 255) & ~(size_t)255;
    return p;
  };
  int*   counts   = (int*)alloc((size_t)N_NODES * 4);
  int*   offs     = (int*)alloc((size_t)(N_NODES + 1) * 4);
  int*   cursor   = (int*)alloc((size_t)N_NODES * 4);
  int*   csr_src  = (int*)alloc((size_t)N_EDGES * 4);
  float* csr_attr = (float*)alloc((size_t)N_EDGES * 16 * 4);
  float* xlr      = (float*)alloc((size_t)N_NODES * 512 * 4);
  float* hF       = (float*)alloc((size_t)N_NODES * 256 * 4);
  unsigned short* hbf0 = (unsigned short*)alloc((size_t)N_NODES * 256 * 2);
  unsigned short* hbf1 = (unsigned short*)alloc((size_t)N_NODES * 256 * 2);
  unsigned short* xbf  = (unsigned short*)alloc((size_t)N_NODES * NODE_DIM * 2);
  unsigned short* WTall = (unsigned short*)alloc((size_t)5 * 512 * 256 * 2);
  float* g        = (float*)alloc((size_t)N_GRAPHS * 256 * 4);

  hipMemsetAsync(counts, 0, (size_t)N_NODES * 4, stream);
  hist_kernel<<<(N_EDGES + 255) / 256, 256, 0, stream>>>(ei + N_EDGES, counts, N_EDGES);
  scan_kernel<<<1, 256, 0, stream>>>(counts, offs, cursor, N_NODES);
  scatter_kernel<<<(N_EDGES + 255) / 256, 256, 0, stream>>>(ei, eattr, cursor, csr_src,
                                                            csr_attr, N_EDGES);
  cvt_x<<<(N_NODES * NODE_DIM / 4 + 255) / 256, 256, 0, stream>>>(x, xbf,
                                                                  N_NODES * NODE_DIM / 4);
  {
    dim3 wgrid(512, 5);
    cvt_w_all<<<wgrid, 256, 0, stream>>>(Wl1, Wr1, Wls, Wrs, WTall);
  }

  for (int layer = 0; layer < 5; ++layer) {
    int K = (layer == 0) ? NODE_DIM : HIDDEN;
    const float* We = (layer == 0) ? We1 : Wes + (size_t)(layer - 1) * EDGE_DIM * HIDDEN;
    const float* bl = (layer == 0) ? bl1 : bls + (layer - 1) * HIDDEN;
    const float* br = (layer == 0) ? br1 : brs + (layer - 1) * HIDDEN;
    const float* at = (layer == 0) ? att1 : atts + (layer - 1) * HIDDEN;
    const float* bc = (layer == 0) ? b1 : bs + (layer - 1) * HIDDEN;
    const unsigned short* Abf = (layer == 0) ? xbf : ((layer & 1) ? hbf0 : hbf1);
    unsigned short* hbf_out = (layer & 1) ? hbf1 : hbf0;
    const unsigned short* WT = WTall + (size_t)layer * 512 * 256;

    dim3 ggrid((N_NODES + 63) / 64, 8);
    gemm_mfma<<<ggrid, 256, 0, stream>>>(Abf, WT, bl, br, xlr, N_NODES, K);
    edge_gat<<<N_NODES / 4, 256, 0, stream>>>(xlr, offs, csr_src, csr_attr, We, at, bc,
                                              bng + layer * HIDDEN, bnb + layer * HIDDEN,
                                              bnm + layer * HIDDEN, bnv + layer * HIDDEN,
                                              hF, hbf_out, (layer == 4) ? 1 : 0);
  }
  pool_kernel<<<N_GRAPHS, 256, 0, stream>>>(hF, batch, g);
  head_kernel<<<4, 256, 0, stream>>>(g, l1w, l1b, l2w, l2b, out);
}